// Round 6
// baseline (22.143 us; speedup 1.0000x reference)
//
#include <hip/hip_runtime.h>

#define NB   16
#define NT   512
#define ND   384
#define NMEL 4096
#define ROWV (ND / 4)      // 96 16B-vectors per row
#define BPB  128           // blocks per batch
#define FPB  (NMEL / BPB)  // 32 frames per block
#define NTHR 256
#define VPT  ((FPB * ROWV) / NTHR)   // 12 vectors per thread
#define GRP  6                        // load-group size (2 groups of 6)

typedef float f32x4 __attribute__((ext_vector_type(4)));

// Fused: each block = (batch b, 32-frame chunk). Shuffle-based scan of the
// masked durations (3 barriers), LDS binary search for the chunk's frame
// indices, then stream 48 KB of gathered rows (load-6/store-6 groups).
// XCD swizzle: blockIdx round-robins over 8 XCDs, so remap such that each
// XCD owns 2 whole batches -> gather working set 1.6 MB < 4 MB local L2.
__global__ __launch_bounds__(NTHR) void dr_fused_kernel(
    const f32x4* __restrict__ batch,     // [NB*NT*ROWV]
    const int*   __restrict__ tl32,      // token_lengths (int32 or int64 layout)
    const int2*  __restrict__ td2,       // [NB][NT/2] int32 durations as int2
    const int*   __restrict__ alpha_ptr,
    f32x4*       __restrict__ out,       // [NB*NMEL*ROWV]
    float*       __restrict__ mel_lens)  // [NB]
{
    // ---- XCD-aware remap (8 XCDs, 2048 blocks, bijective) ----
    const int wid   = (blockIdx.x & 7) * (NB * BPB / 8) + (blockIdx.x >> 3);
    const int b     = wid >> 7;               // / BPB
    const int chunk = wid & (BPB - 1);
    const int t     = threadIdx.x;
    const int lane  = t & 63;
    const int w     = t >> 6;                 // wave id, 0..3

    __shared__ int scsum[NT];                 // inclusive cumsum
    __shared__ int wtot[4];
    __shared__ int s_idx[FPB];

    // ---- token_lengths element-width detection ----
    // lengths in [1, NT]: int64 (LE) => odd int32 slots are zero high-words.
    bool is64 = true;
    #pragma unroll
    for (int i = 1; i < NB; i += 2) {
        if (tl32[i] != 0) is64 = false;
    }
    const int len = is64 ? tl32[2 * b] : tl32[b];

    // ---- alpha decode (bench uses 1; accept int-bits or float-bits) ----
    const int   araw  = alpha_ptr[0];
    const float abits = __int_as_float(araw);
    const bool  alpha_one = (araw == 1) || (abits == 1.0f);

    // ---- load 2 durations per thread, mask, pair-sum ----
    const int i0 = 2 * t, i1 = 2 * t + 1;
    int2 dd = td2[b * (NT / 2) + t];
    int d0 = dd.x, d1 = dd.y;
    if (!alpha_one) {
        float a = (abits > 0.001f && abits < 1000.0f) ? abits : (float)araw;
        d0 = (int)rintf((float)d0 * a);   // round-half-even, matches jnp.round
        d1 = (int)rintf((float)d1 * a);
    }
    if (i0 >= len) d0 = 0;
    if (i1 >= len) d1 = 0;

    // ---- wave-inclusive scan of pair sums (6 shfl_up steps, no barriers) ----
    int sc = d0 + d1;
    #pragma unroll
    for (int off = 1; off < 64; off <<= 1) {
        int v = __shfl_up(sc, off, 64);
        if (lane >= off) sc += v;
    }
    if (lane == 63) wtot[w] = sc;
    __syncthreads();                                        // barrier 1

    int woff = 0, total = 0;
    #pragma unroll
    for (int j = 0; j < 4; ++j) {
        const int wv = wtot[j];
        total += wv;
        if (j < w) woff += wv;
    }
    const int S = sc + woff;       // inclusive csum through element i1
    scsum[i1] = S;
    scsum[i0] = S - d1;
    __syncthreads();                                        // barrier 2

    if (chunk == 0 && t == 0) mel_lens[b] = (float)total;

    // ---- resolve this chunk's 32 frame indices (one wave) ----
    const int f0 = chunk * FPB;
    if (t < FPB) {
        const int f = f0 + t;
        // searchsorted(side='right'): first idx with csum[idx] > f
        int lo = 0, hi = NT;
        while (lo < hi) {
            const int mid = (lo + hi) >> 1;
            if (scsum[mid] <= f) lo = mid + 1; else hi = mid;
        }
        int idx = (lo < NT) ? lo : (NT - 1);  // clip to T-1
        s_idx[t] = (f < total) ? idx : -1;
    }
    __syncthreads();                                        // barrier 3

    // ---- gather + stream: 3072 vectors/block, 12/thread, groups of 6 ----
    const f32x4* brow = batch + (size_t)b * NT * ROWV;   // block's batch base
    f32x4*       orow = out + ((size_t)b * NMEL + f0) * ROWV;
    #pragma unroll
    for (int g = 0; g < VPT / GRP; ++g) {
        int   ee[GRP];
        f32x4 v[GRP];
        // phase 1: issue GRP unconditional loads (clamped row for invalid
        // frames — row 0 is cache-hot, negligible extra traffic)
        #pragma unroll
        for (int i = 0; i < GRP; ++i) {
            const int e   = t + (g * GRP + i) * NTHR;
            const int fl  = e / ROWV;
            const int col = e - fl * ROWV;
            const int enc = s_idx[fl];
            const int rc  = (enc >= 0 ? enc : 0) * ROWV + col;  // 32-bit, <786432
            f32x4 vv = brow[rc];
            v[i]  = (enc >= 0) ? vv : (f32x4)(0.f);
            ee[i] = e;
        }
        // phase 2: GRP coalesced stores
        #pragma unroll
        for (int i = 0; i < GRP; ++i) {
            orow[ee[i]] = v[i];
        }
    }
}

extern "C" void kernel_launch(void* const* d_in, const int* in_sizes, int n_in,
                              void* d_out, int out_size, void* d_ws, size_t ws_size,
                              hipStream_t stream) {
    const float* batch = (const float*)d_in[0];
    const int*   tl    = (const int*)d_in[1];
    const int*   td    = (const int*)d_in[2];
    const int*   alpha = (const int*)d_in[3];

    float* out      = (float*)d_out;
    float* mel_lens = out + (size_t)NB * NMEL * ND;  // second tuple output

    dr_fused_kernel<<<NB * BPB, NTHR, 0, stream>>>(
        (const f32x4*)batch, tl, (const int2*)td, alpha, (f32x4*)out, mel_lens);
}

// Round 7
// 21.289 us; speedup vs baseline: 1.0402x; 1.0402x over previous
//
#include <hip/hip_runtime.h>

#define NB   16
#define NT   512
#define ND   384
#define NMEL 4096
#define ROWV (ND / 4)      // 96 16B-vectors per row
#define BPB  128           // blocks per batch
#define FPB  (NMEL / BPB)  // 32 frames per block
#define NTHR 256
#define VPT  ((FPB * ROWV) / NTHR)   // 12 vectors per thread
#define GRP  6                        // load-group size (2 groups of 6)

typedef float f32x4 __attribute__((ext_vector_type(4)));

// Fused: each block = (batch b, 32-frame chunk). Shuffle-based scan of the
// masked durations (3 barriers), LDS binary search for the chunk's frame
// indices, then stream 48 KB of gathered rows (load-6/store-6 groups).
// Invalid frames (f >= mel_len) take a masked branch that issues NO load:
// zero-region waves are pure store streams.
__global__ __launch_bounds__(NTHR) void dr_fused_kernel(
    const f32x4* __restrict__ batch,     // [NB*NT*ROWV]
    const int*   __restrict__ tl32,      // token_lengths (int32 or int64 layout)
    const int2*  __restrict__ td2,       // [NB][NT/2] int32 durations as int2
    const int*   __restrict__ alpha_ptr,
    f32x4*       __restrict__ out,       // [NB*NMEL*ROWV]
    float*       __restrict__ mel_lens)  // [NB]
{
    // ---- XCD-aware remap (8 XCDs, 2048 blocks, bijective; neutral but free)
    const int wid   = (blockIdx.x & 7) * (NB * BPB / 8) + (blockIdx.x >> 3);
    const int b     = wid >> 7;               // / BPB
    const int chunk = wid & (BPB - 1);
    const int t     = threadIdx.x;
    const int lane  = t & 63;
    const int w     = t >> 6;                 // wave id, 0..3

    __shared__ int scsum[NT];                 // inclusive cumsum
    __shared__ int wtot[4];
    __shared__ int s_idx[FPB];

    // ---- token_lengths element-width detection ----
    // lengths in [1, NT]: int64 (LE) => odd int32 slots are zero high-words.
    bool is64 = true;
    #pragma unroll
    for (int i = 1; i < NB; i += 2) {
        if (tl32[i] != 0) is64 = false;
    }
    const int len = is64 ? tl32[2 * b] : tl32[b];

    // ---- alpha decode (bench uses 1; accept int-bits or float-bits) ----
    const int   araw  = alpha_ptr[0];
    const float abits = __int_as_float(araw);
    const bool  alpha_one = (araw == 1) || (abits == 1.0f);

    // ---- load 2 durations per thread, mask, pair-sum ----
    const int i0 = 2 * t, i1 = 2 * t + 1;
    int2 dd = td2[b * (NT / 2) + t];
    int d0 = dd.x, d1 = dd.y;
    if (!alpha_one) {
        float a = (abits > 0.001f && abits < 1000.0f) ? abits : (float)araw;
        d0 = (int)rintf((float)d0 * a);   // round-half-even, matches jnp.round
        d1 = (int)rintf((float)d1 * a);
    }
    if (i0 >= len) d0 = 0;
    if (i1 >= len) d1 = 0;

    // ---- wave-inclusive scan of pair sums (6 shfl_up steps, no barriers) ----
    int sc = d0 + d1;
    #pragma unroll
    for (int off = 1; off < 64; off <<= 1) {
        int v = __shfl_up(sc, off, 64);
        if (lane >= off) sc += v;
    }
    if (lane == 63) wtot[w] = sc;
    __syncthreads();                                        // barrier 1

    int woff = 0, total = 0;
    #pragma unroll
    for (int j = 0; j < 4; ++j) {
        const int wv = wtot[j];
        total += wv;
        if (j < w) woff += wv;
    }
    const int S = sc + woff;       // inclusive csum through element i1
    scsum[i1] = S;
    scsum[i0] = S - d1;
    __syncthreads();                                        // barrier 2

    if (chunk == 0 && t == 0) mel_lens[b] = (float)total;

    // ---- resolve this chunk's 32 frame indices (one wave) ----
    const int f0 = chunk * FPB;
    if (t < FPB) {
        const int f = f0 + t;
        // searchsorted(side='right'): first idx with csum[idx] > f
        int lo = 0, hi = NT;
        while (lo < hi) {
            const int mid = (lo + hi) >> 1;
            if (scsum[mid] <= f) lo = mid + 1; else hi = mid;
        }
        s_idx[t] = (lo < NT) ? lo : (NT - 1);  // clip to T-1
    }
    __syncthreads();                                        // barrier 3

    // valid vectors in this chunk: frames with f0+fl < total
    const int nvalid = min(max(total - f0, 0), FPB);
    const int vlimit = nvalid * ROWV;          // block-uniform

    // ---- gather + stream: 3072 vectors/block, 12/thread, groups of 6 ----
    const f32x4* brow = batch + (size_t)b * NT * ROWV;   // block's batch base
    f32x4*       orow = out + ((size_t)b * NMEL + f0) * ROWV;
    #pragma unroll
    for (int g = 0; g < VPT / GRP; ++g) {
        f32x4 v[GRP];
        // phase 1: masked loads — invalid elements issue NO memory op
        #pragma unroll
        for (int i = 0; i < GRP; ++i) {
            const int e = t + (g * GRP + i) * NTHR;
            f32x4 vv = (f32x4)(0.f);
            if (e < vlimit) {
                const int fl  = e / ROWV;
                const int col = e - fl * ROWV;
                const int enc = s_idx[fl];                 // >= 0 guaranteed
                vv = brow[enc * ROWV + col];               // 32-bit idx, <786432
            }
            v[i] = vv;
        }
        // phase 2: GRP coalesced stores
        #pragma unroll
        for (int i = 0; i < GRP; ++i) {
            orow[t + (g * GRP + i) * NTHR] = v[i];
        }
    }
}

extern "C" void kernel_launch(void* const* d_in, const int* in_sizes, int n_in,
                              void* d_out, int out_size, void* d_ws, size_t ws_size,
                              hipStream_t stream) {
    const float* batch = (const float*)d_in[0];
    const int*   tl    = (const int*)d_in[1];
    const int*   td    = (const int*)d_in[2];
    const int*   alpha = (const int*)d_in[3];

    float* out      = (float*)d_out;
    float* mel_lens = out + (size_t)NB * NMEL * ND;  // second tuple output

    dr_fused_kernel<<<NB * BPB, NTHR, 0, stream>>>(
        (const f32x4*)batch, tl, (const int2*)td, alpha, (f32x4*)out, mel_lens);
}